// Round 6
// baseline (916.104 us; speedup 1.0000x reference)
//
#include <hip/hip_runtime.h>

typedef __attribute__((ext_vector_type(4))) _Float16 f16x4;
typedef __attribute__((ext_vector_type(4))) float f32x4;

#define NB 4096
#define TT 200
#define DD 64
#define H0 128
#define H1 64
#define FF 128      // shared feature dim: [k ; q*k]
#define PIT 132     // LDS pitch in halfs: 264B = 66 dw == 2 mod 32

// Shared-weight DIN attention. Algebra:
//   h0 = relu( x @ W' + cb ),  x = [k ; q*k] (128 feats),
//   W' = [[W0b - W0c];[W0d]] (b-independent!),  cb = b0 + q@(W0a+W0c)
//   h1 = relu(h0 @ W1 + b1); logit = h1.Wf; masked softmax; pool v.
// Block = 2 consecutive b's; waves (0,1)->b0, (2,3)->b1, strips interleaved.
// Transposed MFMA chain (A=weights from LDS, B=activations in regs):
// layer0 D-frag == layer1 B-frag, so h0 never touches LDS.
// Softmax + v-pooling fused as post-barrier phases per 128-thread group.
// launch_bounds(256,3): R2/R4/R5 showed (256,4) and heavy unroll force
// spills (~1.5GB scratch traffic); unroll capped at 2, regs ~95+acc.
__global__ __launch_bounds__(256, 3)
void din_attn(const float* __restrict__ q, const float* __restrict__ k,
              const float* __restrict__ v, const int* __restrict__ mask,
              const float* __restrict__ W0, const float* __restrict__ b0,
              const float* __restrict__ W1, const float* __restrict__ b1,
              const float* __restrict__ Wf, float* __restrict__ out)
{
  const int bid  = blockIdx.x;
  const int tid  = threadIdx.x;
  const int lane = tid & 63;
  const int wid  = tid >> 6;
  const int r16  = lane & 15;   // t-col within strip / A-row select
  const int g4   = lane >> 4;   // k-subgroup / D row-subgroup

  __shared__ __align__(16) _Float16 WpT[H0 * PIT];  // [h][f]   33 KB
  __shared__ __align__(16) _Float16 W1T[H1 * PIT];  // [j][h]   17 KB
  __shared__ float cbS[2 * H0];
  __shared__ float sP[2 * 208];
  __shared__ float b1S[H1];
  __shared__ float WfS[H1];
  __shared__ float red[8];

  // ---- stage shared weights (b-independent) ----
  #pragma unroll 4
  for (int i = 0; i < 64; ++i) {          // W' 128x128
    int idx = i * 256 + tid;
    int h = idx >> 7, f = idx & 127;
    float val = (f < 64) ? (W0[(64 + f) * H0 + h] - W0[(128 + f) * H0 + h])
                         : W0[(128 + f) * H0 + h];   // 128+f = 192+(f-64)
    WpT[h * PIT + f] = (_Float16)val;
  }
  #pragma unroll 4
  for (int i = 0; i < 32; ++i) {          // W1^T 64x128
    int idx = i * 256 + tid;
    int j = idx & 63, hh0 = idx >> 6;
    W1T[j * PIT + hh0] = (_Float16)W1[hh0 * H1 + j];
  }
  if (tid < H1) { b1S[tid] = b1[tid]; WfS[tid] = Wf[tid]; }
  // ---- per-b bias cb (2 b's, 256 threads) ----
  {
    int h = tid & 127, blc = tid >> 7;
    const float* qc = q + (2 * bid + blc) * DD;
    float s = 0.f;
    #pragma unroll 8
    for (int d = 0; d < DD; ++d)
      s += qc[d] * (W0[d * H0 + h] + W0[(128 + d) * H0 + h]);
    cbS[blc * H0 + h] = s + b0[h];
  }

  // ---- wave-level setup: wave pair (wid>>1) owns b_local, sub-strips ----
  const int blw = wid >> 1;
  const int sub = wid & 1;
  const int bw  = 2 * bid + blw;
  const float* qw  = q + bw * DD;
  const float* kbw = k + (size_t)bw * TT * DD;
  const int*   mbw = mask + bw * TT;

  float qr[16];
  #pragma unroll
  for (int m = 0; m < 4; ++m)
    #pragma unroll
    for (int j = 0; j < 4; ++j)
      qr[m * 4 + j] = qw[m * 16 + 4 * g4 + j];

  // first strip's k issued before the barrier
  float4 kq[4];
  {
    const int trow = sub * 16 + r16;   // < 200 always
    #pragma unroll
    for (int m = 0; m < 4; ++m)
      kq[m] = *(const float4*)(kbw + trow * DD + m * 16 + 4 * g4);
  }
  __syncthreads();

  // ---- strip loop: logits ----
  for (int s = sub; s < 13; s += 2) {
    const int t0   = s * 16;
    const int trow = t0 + r16;
    const bool tv  = trow < TT;
    int mm = tv ? mbw[trow] : -1;

    // build B-frags: f<64 -> k, f>=64 -> k*q ; then prefetch next strip
    f16x4 bh[8];
    #pragma unroll
    for (int m = 0; m < 4; ++m) {
      float kf[4] = {kq[m].x, kq[m].y, kq[m].z, kq[m].w};
      #pragma unroll
      for (int j = 0; j < 4; ++j) {
        bh[m][j]     = (_Float16)kf[j];
        bh[4 + m][j] = (_Float16)(kf[j] * qr[m * 4 + j]);
      }
    }
    const int sn = s + 2;
    if (sn < 13) {
      const int trn = sn * 16 + r16;
      const bool tvn = trn < TT;
      #pragma unroll
      for (int m = 0; m < 4; ++m) {
        float4 z = {0.f, 0.f, 0.f, 0.f};
        kq[m] = tvn ? *(const float4*)(kbw + trn * DD + m * 16 + 4 * g4) : z;
      }
    }

    // layer0^T: h0t[h=c*16+4g4+r][t0+r16]
    f16x4 hhv[8];
    #pragma unroll 2
    for (int c = 0; c < 8; ++c) {
      const _Float16* base = &WpT[(c * 16 + r16) * PIT];
      f32x4 acc = {0.f, 0.f, 0.f, 0.f};
      #pragma unroll
      for (int ks = 0; ks < 8; ++ks) {
        f16x4 af = *(const f16x4*)(base + ks * 16 + 4 * g4);
        acc = __builtin_amdgcn_mfma_f32_16x16x16f16(af, bh[ks], acc, 0, 0, 0);
      }
      f32x4 cb4 = *(const f32x4*)(&cbS[blw * H0 + c * 16 + 4 * g4]);
      #pragma unroll
      for (int r = 0; r < 4; ++r) {
        float hv = acc[r] + cb4[r];
        hhv[c][r] = (_Float16)(hv > 0.f ? hv : 0.f);
      }
    }

    // layer1^T + logit
    float p = 0.f;
    #pragma unroll 2
    for (int c1 = 0; c1 < 4; ++c1) {
      const _Float16* base = &W1T[(c1 * 16 + r16) * PIT];
      f32x4 acc = {0.f, 0.f, 0.f, 0.f};
      #pragma unroll
      for (int ks = 0; ks < 8; ++ks) {
        f16x4 af = *(const f16x4*)(base + ks * 16 + 4 * g4);
        acc = __builtin_amdgcn_mfma_f32_16x16x16f16(af, hhv[ks], acc, 0, 0, 0);
      }
      f32x4 b14 = *(const f32x4*)(&b1S[c1 * 16 + 4 * g4]);
      f32x4 wf4 = *(const f32x4*)(&WfS[c1 * 16 + 4 * g4]);
      #pragma unroll
      for (int r = 0; r < 4; ++r) {
        float h1 = acc[r] + b14[r];
        h1 = h1 > 0.f ? h1 : 0.f;
        p = fmaf(h1, wf4[r], p);
      }
    }

    p += __shfl_xor(p, 16, 64);
    p += __shfl_xor(p, 32, 64);
    p = (mm == 1) ? p : (mm == 0 ? -1e30f : -2e30f);
    if (g4 == 0) sP[blw * 208 + t0 + r16] = p;
  }
  __syncthreads();

  // ---- softmax per b (128-thread groups) ----
  const int l128 = tid & 127;
  const int blg  = tid >> 7;
  float v1 = sP[blg * 208 + l128];
  const bool h2 = l128 < 80;
  float v2 = h2 ? sP[blg * 208 + 128 + l128] : -3e30f;
  float mx = fmaxf(v1, v2);
  #pragma unroll
  for (int off = 32; off >= 1; off >>= 1) mx = fmaxf(mx, __shfl_xor(mx, off, 64));
  if (lane == 0) red[wid] = mx;
  __syncthreads();
  const float M = fmaxf(red[2 * blg], red[2 * blg + 1]);
  float e1 = __expf(v1 - M);
  float e2 = h2 ? __expf(v2 - M) : 0.f;
  sP[blg * 208 + l128] = e1;
  if (h2) sP[blg * 208 + 128 + l128] = e2;
  float se = e1 + e2;
  #pragma unroll
  for (int off = 32; off >= 1; off >>= 1) se += __shfl_xor(se, off, 64);
  if (lane == 0) red[4 + wid] = se;
  __syncthreads();
  const float rcpS = 1.f / (red[4 + 2 * blg] + red[5 + 2 * blg]);

  // ---- pooling: group thread = (tg, dq); float4 v loads, t stride 8 ----
  {
    const int dq = l128 & 15;
    const int tg = l128 >> 4;
    const float* vbl = v + (size_t)(2 * bid + blg) * TT * DD;
    f32x4 o4 = {0.f, 0.f, 0.f, 0.f};
    #pragma unroll 5
    for (int t = tg; t < TT; t += 8) {
      float w = sP[blg * 208 + t];
      f32x4 v4 = *(const f32x4*)(vbl + t * DD + dq * 4);
      #pragma unroll
      for (int i = 0; i < 4; ++i) o4[i] = fmaf(w, v4[i], o4[i]);
    }
    float* pool = (float*)WpT;   // strips done; reuse weight LDS
    *(f32x4*)(pool + ((blg * 8 + tg) * 16 + dq) * 4) = o4;
  }
  __syncthreads();

  if (l128 < 16) {
    const float* pool = (const float*)WpT;
    f32x4 acc = {0.f, 0.f, 0.f, 0.f};
    #pragma unroll
    for (int tg2 = 0; tg2 < 8; ++tg2) {
      f32x4 pv = *(const f32x4*)(pool + ((blg * 8 + tg2) * 16 + l128) * 4);
      #pragma unroll
      for (int i = 0; i < 4; ++i) acc[i] += pv[i];
    }
    #pragma unroll
    for (int i = 0; i < 4; ++i) acc[i] *= rcpS;
    *(f32x4*)(out + (2 * bid + blg) * DD + l128 * 4) = acc;
  }
}

extern "C" void kernel_launch(void* const* d_in, const int* in_sizes, int n_in,
                              void* d_out, int out_size, void* d_ws, size_t ws_size,
                              hipStream_t stream) {
  const float* q    = (const float*)d_in[0];
  const float* k    = (const float*)d_in[1];
  const float* v    = (const float*)d_in[2];
  const int*   mask = (const int*)d_in[3];
  const float* W0   = (const float*)d_in[4];
  const float* b0   = (const float*)d_in[5];
  const float* W1   = (const float*)d_in[6];
  const float* b1   = (const float*)d_in[7];
  const float* Wf   = (const float*)d_in[8];
  float* out = (float*)d_out;
  din_attn<<<dim3(NB / 2), dim3(256), 0, stream>>>(q, k, v, mask, W0, b0, W1, b1, Wf, out);
}

// Round 7
// 153.268 us; speedup vs baseline: 5.9771x; 5.9771x over previous
//
#include <hip/hip_runtime.h>

typedef __attribute__((ext_vector_type(4))) _Float16 f16x4;
typedef __attribute__((ext_vector_type(4))) float f32x4;

#define NB 4096
#define TT 200
#define DD 64
#define H0 128
#define H1 64
#define MP 76    // MhT pitch (halfs): 152B, 8B-aligned, row term 6*r16 mod 32 -> spread
#define WP 140   // W1T pitch (halfs): 280B, same property

// Transposed-GEMM DIN attention, fp16 weights/activations, fp32 accum/softmax.
//   M_b = W0b - W0c + diag(q) W0d  (64x128 fp16 LDS [h][d], pitch-76)
//   layer0^T frag c -> IMMEDIATELY folded into 4 persistent layer1 accs
//   (acc1[c1], inner loops fully unrolled -> all register arrays statically
//   indexed; outer c loop unroll 1 -> bounded live range, ~70 arch VGPRs).
//   Logits -> LDS; exact softmax pass; v-streaming pooling pass.
// R2/R4: (256,4) forces 64/64 arch/acc split -> spill. R5: full unroll
// inflated live set past 84 -> spill. R6: partial unroll + reg arrays ->
// VALU select-ladder storm (72% VALUBusy). This version avoids all three.
__global__ __launch_bounds__(256, 3)
void din_attn(const float* __restrict__ q, const float* __restrict__ k,
              const float* __restrict__ v, const int* __restrict__ mask,
              const float* __restrict__ W0, const float* __restrict__ b0,
              const float* __restrict__ W1, const float* __restrict__ b1,
              const float* __restrict__ Wf, float* __restrict__ out)
{
  const int b    = blockIdx.x;
  const int tid  = threadIdx.x;
  const int lane = tid & 63;
  const int wid  = tid >> 6;
  const int r16  = lane & 15;   // t-col within strip / A-row select
  const int g4   = lane >> 4;   // k-subgroup / D row-subgroup

  __shared__ __align__(16) _Float16 MhT[H0 * MP];   // 19.0 KB
  __shared__ __align__(16) _Float16 W1T[H1 * WP];   // 17.5 KB
  __shared__ float cbS[H0];
  __shared__ float b1S[H1];
  __shared__ float WfS[H1];
  __shared__ float sP[208];
  __shared__ float red[8];
  __shared__ float pool[256];   // cb partials, then pooling partials

  const float* qb = q + b * DD;
  const float* kb = k + (size_t)b * TT * DD;
  const float* vb = v + (size_t)b * TT * DD;
  const int*   mb = mask + b * TT;

  // ---- prologue ----
  {
    int h = tid & 127, half = tid >> 7;
    float s = 0.f;
    #pragma unroll 8
    for (int i = 0; i < 32; ++i) {
      int d = half * 32 + i;
      s += qb[d] * (W0[d * H0 + h] + W0[(128 + d) * H0 + h]);
    }
    pool[tid] = s;
  }
  #pragma unroll 4
  for (int i = 0; i < 32; ++i) {      // M_b^T -> LDS [h][d]
    int idx = i * 256 + tid;
    int h = idx & 127, d = idx >> 7;
    float val = W0[(64 + d) * H0 + h] - W0[(128 + d) * H0 + h]
              + qb[d] * W0[(192 + d) * H0 + h];
    MhT[h * MP + d] = (_Float16)val;
  }
  #pragma unroll 4
  for (int i = 0; i < 32; ++i) {      // W1^T -> LDS [j][h]
    int idx = i * 256 + tid;
    int hh = idx >> 6, j = idx & 63;
    W1T[j * WP + hh] = (_Float16)W1[idx];
  }
  if (tid < H1) { b1S[tid] = b1[tid]; WfS[tid] = Wf[tid]; }
  __syncthreads();
  if (tid < H0) cbS[tid] = pool[tid] + pool[tid + 128] + b0[tid];

  // first strip's k issued before the barrier
  float4 kq[4];
  {
    const int trow = wid * 16 + r16;   // always < 200
    #pragma unroll
    for (int m = 0; m < 4; ++m)
      kq[m] = *(const float4*)(kb + trow * DD + m * 16 + 4 * g4);
  }
  __syncthreads();

  // ---- pass 1: logits ----
  #pragma unroll 1
  for (int s = wid; s < 13; s += 4) {
    const int t0   = s * 16;
    const int trow = t0 + r16;
    const bool tv  = trow < TT;
    int mm = tv ? mb[trow] : -1;

    f16x4 bh[4];
    #pragma unroll
    for (int m = 0; m < 4; ++m) {
      float kf[4] = {kq[m].x, kq[m].y, kq[m].z, kq[m].w};
      #pragma unroll
      for (int j = 0; j < 4; ++j) bh[m][j] = (_Float16)kf[j];
    }
    const int sn = s + 4;
    if (sn < 13) {
      const int trn = sn * 16 + r16;
      const bool tvn = trn < TT;
      #pragma unroll
      for (int m = 0; m < 4; ++m) {
        float4 z = {0.f, 0.f, 0.f, 0.f};
        kq[m] = tvn ? *(const float4*)(kb + trn * DD + m * 16 + 4 * g4) : z;
      }
    }

    f32x4 acc1[4];
    #pragma unroll
    for (int c1 = 0; c1 < 4; ++c1) acc1[c1] = (f32x4){0.f, 0.f, 0.f, 0.f};

    // outer c loop NOT unrolled: nothing register-resident is indexed by c
    #pragma unroll 1
    for (int c = 0; c < 8; ++c) {
      const _Float16* mrow = &MhT[(c * 16 + r16) * MP];
      f32x4 a0 = {0.f, 0.f, 0.f, 0.f};
      #pragma unroll
      for (int ks = 0; ks < 4; ++ks) {
        f16x4 af = *(const f16x4*)(mrow + ks * 16 + 4 * g4);
        a0 = __builtin_amdgcn_mfma_f32_16x16x16f16(af, bh[ks], a0, 0, 0, 0);
      }
      f32x4 cb4 = *(const f32x4*)(&cbS[c * 16 + 4 * g4]);
      f16x4 hf;
      #pragma unroll
      for (int r = 0; r < 4; ++r) {
        float hv = a0[r] + cb4[r];
        hf[r] = (_Float16)(hv > 0.f ? hv : 0.f);
      }
      #pragma unroll
      for (int c1 = 0; c1 < 4; ++c1) {
        f16x4 af1 = *(const f16x4*)(&W1T[(c1 * 16 + r16) * WP + c * 16 + 4 * g4]);
        acc1[c1] = __builtin_amdgcn_mfma_f32_16x16x16f16(af1, hf, acc1[c1], 0, 0, 0);
      }
    }

    float p = 0.f;
    #pragma unroll
    for (int c1 = 0; c1 < 4; ++c1) {
      f32x4 b14 = *(const f32x4*)(&b1S[c1 * 16 + 4 * g4]);
      f32x4 wf4 = *(const f32x4*)(&WfS[c1 * 16 + 4 * g4]);
      #pragma unroll
      for (int r = 0; r < 4; ++r) {
        float h1 = acc1[c1][r] + b14[r];
        h1 = h1 > 0.f ? h1 : 0.f;
        p = fmaf(h1, wf4[r], p);
      }
    }

    p += __shfl_xor(p, 16, 64);
    p += __shfl_xor(p, 32, 64);
    p = (mm == 1) ? p : (mm == 0 ? -1e30f : -2e30f);
    if (g4 == 0) sP[t0 + r16] = p;
  }
  __syncthreads();

  // ---- pass 2: exact softmax over sP[0..207], store unnormalized e ----
  float rcpS;
  {
    float val = (tid < 208) ? sP[tid] : -3e30f;
    float mx = val;
    #pragma unroll
    for (int off = 32; off >= 1; off >>= 1) mx = fmaxf(mx, __shfl_xor(mx, off, 64));
    if (lane == 0) red[wid] = mx;
    __syncthreads();
    float M = fmaxf(fmaxf(red[0], red[1]), fmaxf(red[2], red[3]));
    float e = (tid < 208) ? __expf(val - M) : 0.f;
    float se = e;
    #pragma unroll
    for (int off = 32; off >= 1; off >>= 1) se += __shfl_xor(se, off, 64);
    if (lane == 0) red[4 + wid] = se;
    __syncthreads();
    rcpS = 1.f / ((red[4] + red[5]) + (red[6] + red[7]));
    if (tid < 208) sP[tid] = e;
  }
  __syncthreads();

  // ---- pass 3: pooling, wave w covers t in [w*52, w*52+52) ----
  {
    float o0 = 0.f, o1 = 0.f, o2 = 0.f, o3 = 0.f;
    const int tbase = wid * 52;
    #pragma unroll 4
    for (int i = 0; i < 52; i += 4) {
      int t = tbase + i;
      if (t + 3 < TT) {
        o0 = fmaf(sP[t + 0], vb[(t + 0) * DD + lane], o0);
        o1 = fmaf(sP[t + 1], vb[(t + 1) * DD + lane], o1);
        o2 = fmaf(sP[t + 2], vb[(t + 2) * DD + lane], o2);
        o3 = fmaf(sP[t + 3], vb[(t + 3) * DD + lane], o3);
      } else {
        #pragma unroll
        for (int j = 0; j < 4; ++j) {
          int tj = t + j;
          if (tj < TT) o0 = fmaf(sP[tj], vb[tj * DD + lane], o0);
        }
      }
    }
    pool[wid * 64 + lane] = (o0 + o1) + (o2 + o3);
  }
  __syncthreads();

  if (tid < DD)
    out[b * DD + tid] = ((pool[tid] + pool[64 + tid])
                       + (pool[128 + tid] + pool[192 + tid])) * rcpS;
}

extern "C" void kernel_launch(void* const* d_in, const int* in_sizes, int n_in,
                              void* d_out, int out_size, void* d_ws, size_t ws_size,
                              hipStream_t stream) {
  const float* q    = (const float*)d_in[0];
  const float* k    = (const float*)d_in[1];
  const float* v    = (const float*)d_in[2];
  const int*   mask = (const int*)d_in[3];
  const float* W0   = (const float*)d_in[4];
  const float* b0   = (const float*)d_in[5];
  const float* W1   = (const float*)d_in[6];
  const float* b1   = (const float*)d_in[7];
  const float* Wf   = (const float*)d_in[8];
  float* out = (float*)d_out;
  din_attn<<<dim3(NB), dim3(256), 0, stream>>>(q, k, v, mask, W0, b0, W1, b1, Wf, out);
}